// Round 14
// baseline (360.357 us; speedup 1.0000x reference)
//
#include <hip/hip_runtime.h>
#include <cmath>

// ---------------------------------------------------------------------------
// WireframeDetector: NMS -> top-k 300 junctions -> line sampling (bilinear +
// maxpool) -> 3-layer MLP (fp16 MFMA for the two 1024x1024 GEMMs).
// R14: (a) GEMM BM=256 via 512 threads / 8 waves — staged bytes 643->485 MB
//      at the measured ~6 TB/s delivery wall (per-wave subtile still 64x64,
//      avoiding R6's VGPR blowup). (b) lines bucket-sorted by e0 so waves
//      processing lines with a shared junction run adjacently -> L1/L2 tap
//      locality (sample is ~10M scattered line-requests otherwise).
// ---------------------------------------------------------------------------

typedef _Float16 f16;
typedef _Float16 f16x2 __attribute__((ext_vector_type(2)));
typedef _Float16 f16x8 __attribute__((ext_vector_type(8)));
typedef float f32x4 __attribute__((ext_vector_type(4)));

#define HWD 128
#define NPIX 16384            // 128*128
#define TOPK_N 300
#define NLINES 20000
#define MPAD 20224            // 79 * 256
#define KDIM 1024
#define NDIM 1024
#define MAXCAND 4096

// async global->LDS, 16B per lane; LDS dest = wave-uniform base + lane*16
#define G2L(gp, lp) __builtin_amdgcn_global_load_lds( \
    (const __attribute__((address_space(1))) void*)(gp), \
    (__attribute__((address_space(3))) void*)(lp), 16, 0, 0)

// ---------------------------------------------------------------------------
// Fused preprocessing, one dispatch of 764 blocks:
//   blocks 0..127   : transpose loi [C][H][W] fp32 -> loiT [H][W][C] fp16
//   blocks 128..639 : W1/W2 [K][N] fp32 -> K-chunk-tiled fp16
//   blocks 640..703 : 3x3 NMS on jloc, survivors -> cand list (count pre-zeroed)
//   blocks 704..763 : zero out[60000] (consumed by gemm2's atomicAdd epilogue)
// ---------------------------------------------------------------------------
__global__ __launch_bounds__(256) void preproc_kernel(
    const float* __restrict__ loi, f16* __restrict__ loiT,
    const float* __restrict__ W1, f16* __restrict__ W1T,
    const float* __restrict__ W2, f16* __restrict__ W2T,
    const float* __restrict__ jloc, unsigned long long* __restrict__ cand,
    int* __restrict__ count, float* __restrict__ out, int out_n)
{
    const int bid = blockIdx.x;
    const int tid = threadIdx.x;
    if (bid < 128) {
        __shared__ f16 t[128 * 130];     // [x][c], +2 pad kills bank conflicts
        const int y = bid;
        #pragma unroll 4
        for (int it = 0; it < 64; ++it) {
            int idx = it * 256 + tid;    // c-major, x fast -> coalesced read
            int c = idx >> 7, x = idx & 127;
            t[x * 130 + c] = (f16)loi[c * NPIX + y * HWD + x];
        }
        __syncthreads();
        #pragma unroll
        for (int it = 0; it < 8; ++it) {
            int j = it * 256 + tid;      // 2048 chunks of 8 f16
            int x = j >> 4, cc = (j & 15) * 8;
            f16x8 v;
            #pragma unroll
            for (int u = 0; u < 8; ++u) v[u] = t[x * 130 + cc + u];
            *(f16x8*)(loiT + (y * HWD + x) * HWD + cc) = v;
        }
    } else if (bid < 640) {
        const int b = bid - 128;         // 0..511
        const float* W = (b < 256) ? W1 : W2;
        f16* Wt = (b < 256) ? W1T : W2T;
        const int bb = b & 255;
        __shared__ f16 t[64 * 66];
        const int k0 = (bb >> 4) * 64;
        const int n0 = (bb & 15) * 64;
        #pragma unroll 4
        for (int it = 0; it < 16; ++it) {
            int i = it * 256 + tid;      // coalesced read over n
            int r = i >> 6, c = i & 63;
            t[c * 66 + r] = (f16)W[(size_t)(k0 + r) * NDIM + n0 + c];
        }
        __syncthreads();
        #pragma unroll
        for (int it = 0; it < 2; ++it) {
            int j = it * 256 + tid;
            int nr = j >> 3, kc = (j & 7) * 8;
            f16x8 v;
            #pragma unroll
            for (int u = 0; u < 8; ++u) v[u] = t[nr * 66 + kc + u];
            const int kk = k0 + kc;      // multiple of 8
            *(f16x8*)(Wt + ((size_t)(kk >> 5) * NDIM + (n0 + nr)) * 32 + (kk & 31)) = v;
        }
    } else if (bid < 704) {
        const int p = (bid - 640) * 256 + tid;   // 64 blocks x 256 = 16384
        const int y = p >> 7, x = p & 127;
        const float c = jloc[p];
        float m = c;
        for (int dy = -1; dy <= 1; ++dy) {
            int yy = y + dy;
            if (yy < 0 || yy >= HWD) continue;
            for (int dx = -1; dx <= 1; ++dx) {
                int xx = x + dx;
                if (xx < 0 || xx >= HWD) continue;
                m = fmaxf(m, jloc[yy * HWD + xx]);
            }
        }
        if (c == m && c > 0.0f) {
            int pos = atomicAdd(count, 1);
            if (pos < MAXCAND) {
                unsigned int ub = __float_as_uint(c);
                cand[pos] = ((unsigned long long)ub << 32) |
                            (unsigned long long)(0xFFFFFFFFu - (unsigned int)p);
            }
        }
    } else {
        const int base = (bid - 704) * 1024 + tid * 4;   // 60 blocks cover 61440
        #pragma unroll
        for (int u = 0; u < 4; ++u)
            if (base + u < out_n) out[base + u] = 0.f;
    }
}

// ---------------------------------------------------------------------------
// Bucket-sort line ids by start junction e0 (300 buckets). Order only affects
// processing locality, not results. Single block, 1024 threads.
// ---------------------------------------------------------------------------
__global__ __launch_bounds__(1024) void sort_lines_kernel(
    const int* __restrict__ edge_idx, int* __restrict__ order)
{
    __shared__ int hist[TOPK_N];
    __shared__ int base[TOPK_N];
    const int tid = threadIdx.x;
    for (int i = tid; i < TOPK_N; i += 1024) hist[i] = 0;
    __syncthreads();
    for (int i = tid; i < NLINES; i += 1024)
        atomicAdd(&hist[edge_idx[2 * i]], 1);
    __syncthreads();
    if (tid == 0) {
        int acc = 0;
        for (int b = 0; b < TOPK_N; ++b) { base[b] = acc; acc += hist[b]; }
    }
    __syncthreads();
    for (int i = tid; i < NLINES; i += 1024) {
        int pos = atomicAdd(&base[edge_idx[2 * i]], 1);
        order[pos] = i;
    }
}

// ---------------------------------------------------------------------------
// Rank-select top-300, LDS-cached. Keys unique => ranks exact; matches
// jax.lax.top_k order (value desc, index asc).
// ---------------------------------------------------------------------------
__global__ __launch_bounds__(256) void rank_junc_kernel(
    const unsigned long long* __restrict__ cand, const int* __restrict__ count,
    const float* __restrict__ joff, float* __restrict__ juncs /* [300][2] */)
{
    __shared__ unsigned long long keys[MAXCAND];   // 32 KB
    const int n = min(*count, MAXCAND);
    const int t = blockIdx.x * 256 + threadIdx.x;  // 16 blocks = 4096 threads
    for (int i = threadIdx.x; i < n; i += 256)
        keys[i] = cand[i];
    __syncthreads();
    if (t >= n) return;
    const unsigned long long key = keys[t];
    int rank = 0;
    int j = 0;
    for (; j + 4 <= n; j += 4) {
        rank += (keys[j]     > key);
        rank += (keys[j + 1] > key);
        rank += (keys[j + 2] > key);
        rank += (keys[j + 3] > key);
    }
    for (; j < n; ++j) rank += (keys[j] > key);
    if (rank < TOPK_N) {
        unsigned int p = 0xFFFFFFFFu - (unsigned int)(key & 0xFFFFFFFFull);
        // x = idx%w + (sigmoid(joff0)-0.5) + 0.5 = idx%w + sigmoid(joff0)
        float sx = 1.0f / (1.0f + expf(-joff[p]));
        float sy = 1.0f / (1.0f + expf(-joff[NPIX + p]));
        juncs[2 * rank + 0] = (float)(p & 127) + sx;
        juncs[2 * rank + 1] = (float)(p >> 7) + sy;
    }
}

// ---------------------------------------------------------------------------
// Per-line sampling (deduped taps in LDS), processing lines in e0-sorted
// order for L1 tap locality; output row = original line id.
// ---------------------------------------------------------------------------
__global__ __launch_bounds__(256) void sample_kernel(
    const f16* __restrict__ loiT, const float* __restrict__ juncs,
    const int* __restrict__ edge_idx, const int* __restrict__ order,
    f16* __restrict__ feats)
{
    const int wv = threadIdx.x >> 6;
    const int l = order[blockIdx.x * 4 + wv];
    const int lane = threadIdx.x & 63;

    __shared__ int   soff[4][32][4];   // channel-base element offsets
    __shared__ float swt[4][32][4];    // bilinear weights

    if (lane < 32) {
        const int e0 = edge_idx[2 * l], e1 = edge_idx[2 * l + 1];
        const float ux = juncs[2 * e0], uy = juncs[2 * e0 + 1];
        const float vx = juncs[2 * e1], vy = juncs[2 * e1 + 1];
        const int j = lane;
        const float t = (float)j * (1.0f / 31.0f);
        const float px = ux * t + vx * (1.0f - t) - 0.5f;
        const float py = uy * t + vy * (1.0f - t) - 0.5f;
        float fx0 = fminf(fmaxf(floorf(px), 0.0f), 127.0f);
        float fy0 = fminf(fmaxf(floorf(py), 0.0f), 127.0f);
        float fx1 = fminf(fx0 + 1.0f, 127.0f);
        float fy1 = fminf(fy0 + 1.0f, 127.0f);
        int ix0 = (int)fx0, iy0 = (int)fy0, ix1 = (int)fx1, iy1 = (int)fy1;
        soff[wv][j][0] = (iy0 * HWD + ix0) * HWD;
        soff[wv][j][1] = (iy1 * HWD + ix0) * HWD;
        soff[wv][j][2] = (iy0 * HWD + ix1) * HWD;
        soff[wv][j][3] = (iy1 * HWD + ix1) * HWD;
        swt[wv][j][0] = (fy1 - py) * (fx1 - px);
        swt[wv][j][1] = (py - fy0) * (fx1 - px);
        swt[wv][j][2] = (fy1 - py) * (px - fx0);
        swt[wv][j][3] = (py - fy0) * (px - fx0);
    }
    __syncthreads();

    const int c2 = lane * 2;
    f16x8 o0, o1;
    #pragma unroll
    for (int p = 0; p < 8; ++p) {
        float m0 = -INFINITY, m1 = -INFINITY;
        #pragma unroll
        for (int jj = 0; jj < 4; ++jj) {
            const int j = p * 4 + jj;
            const int b00 = soff[wv][j][0], b10 = soff[wv][j][1];
            const int b01 = soff[wv][j][2], b11 = soff[wv][j][3];
            const float w00 = swt[wv][j][0], w10 = swt[wv][j][1];
            const float w01 = swt[wv][j][2], w11 = swt[wv][j][3];
            f16x2 v00 = *(const f16x2*)(loiT + b00 + c2);
            f16x2 v10 = *(const f16x2*)(loiT + b10 + c2);
            f16x2 v01 = *(const f16x2*)(loiT + b01 + c2);
            f16x2 v11 = *(const f16x2*)(loiT + b11 + c2);
            float s0 = (float)v00.x * w00 + (float)v10.x * w10 +
                       (float)v01.x * w01 + (float)v11.x * w11;
            float s1 = (float)v00.y * w00 + (float)v10.y * w10 +
                       (float)v01.y * w01 + (float)v11.y * w11;
            m0 = fmaxf(m0, s0);
            m1 = fmaxf(m1, s1);
        }
        o0[p] = (f16)m0;   // feature k = 16*lane + p
        o1[p] = (f16)m1;   // feature k = 16*lane + 8 + p
    }
    // tiled: (l, k) -> ((k>>5)*MPAD + l)*32 + (k&31)
    f16* dst = feats + ((size_t)(lane >> 1) * MPAD + l) * 32 + (lane & 1) * 16;
    *(f16x8*)(dst) = o0;
    *(f16x8*)(dst + 8) = o1;
}

// ---------------------------------------------------------------------------
// GEMM: 256x128 tile, 512 threads (8 waves: 4 wm x 2 wn, 64x64 subtile each
// -> acc[4][4], ~60 VGPR). Two BK=32 tiles per round, one vmcnt(0)+barrier
// drain per 64 MFMAs. Operands K-chunk-tiled (contiguous staging). Staged
// bytes per GEMM 643->485 MB at the ~6 TB/s delivery wall (R2-R12 sweep).
// LDS 48 KB -> 3 blocks/CU.
// head=0: C = relu(A@Bt^T + bias), stored K-chunk-tiled fp16.
// head=1: v = relu(A@Bt^T + bias); out[m][j] += v . W3  (atomicAdd, + b3 once)
// ---------------------------------------------------------------------------
__global__ __launch_bounds__(512) void gemm_bias_relu_kernel(
    const f16* __restrict__ A, const f16* __restrict__ Bt,
    const float* __restrict__ bias, f16* __restrict__ C,
    const float* __restrict__ W3, const float* __restrict__ b3,
    float* __restrict__ out, int K, int head)
{
    const int tid = threadIdx.x;
    const int wave = tid >> 6, lane = tid & 63;
    const int wm = wave >> 1, wn = wave & 1;    // wm 0..3, wn 0..1
    const int m0 = blockIdx.x * 256;
    const int n0 = blockIdx.y * 128;

    __shared__ f16 sA0[256 * 32];   // 16 KB
    __shared__ f16 sA1[256 * 32];
    __shared__ f16 sB0[128 * 32];   // 8 KB
    __shared__ f16 sB1[128 * 32];

    f32x4 acc[4][4];
    #pragma unroll
    for (int mi = 0; mi < 4; ++mi)
        #pragma unroll
        for (int ni = 0; ni < 4; ++ni)
            acc[mi][ni] = (f32x4){0.f, 0.f, 0.f, 0.f};

    // Tiled staging, flat copy (global order == LDS order):
    // A k-chunk tile = contiguous 16 KB (16 segs of 1 KB), wave w stages segs
    // {w, w+8}; B tile = 8 KB (8 segs), wave w stages seg w.
    const size_t strideA = (size_t)MPAD * 32;   // f16 per k-chunk
    const size_t strideB = (size_t)NDIM * 32;
    const f16* gA = A + (size_t)m0 * 32 + lane * 8;
    const f16* gB = Bt + (size_t)n0 * 32 + lane * 8;
    const int sa0 = wave * 512;                 // + lane*16B implicit
    const int sa1 = (wave + 8) * 512;
    const int sb = wave * 512;

    const int col16 = lane & 15;
    const int kq = (lane >> 4) * 8;

    const int NC = K >> 5;                      // 32 k-chunks
    for (int c0 = 0; c0 < NC; c0 += 2) {
        const f16* a0 = gA + (size_t)c0 * strideA;
        const f16* a1 = a0 + strideA;
        const f16* b0 = gB + (size_t)c0 * strideB;
        const f16* b1 = b0 + strideB;
        __syncthreads();                      // prev round's LDS reads complete
        G2L(a0 + sa0, sA0 + sa0);
        G2L(a0 + sa1, sA0 + sa1);
        G2L(b0 + sb, sB0 + sb);
        G2L(a1 + sa0, sA1 + sa0);
        G2L(a1 + sa1, sA1 + sa1);
        G2L(b1 + sb, sB1 + sb);
        __builtin_amdgcn_s_waitcnt(0x0f70);   // vmcnt(0): own DMA done
        __syncthreads();                      // all waves' DMA done

        {
            f16x8 af[4], bf[4];
            #pragma unroll
            for (int i = 0; i < 4; ++i) {
                af[i] = *(const f16x8*)(sA0 + (wm * 64 + i * 16 + col16) * 32 + kq);
                bf[i] = *(const f16x8*)(sB0 + (wn * 64 + i * 16 + col16) * 32 + kq);
            }
            #pragma unroll
            for (int mi = 0; mi < 4; ++mi)
                #pragma unroll
                for (int ni = 0; ni < 4; ++ni)
                    acc[mi][ni] = __builtin_amdgcn_mfma_f32_16x16x32_f16(
                        af[mi], bf[ni], acc[mi][ni], 0, 0, 0);
        }
        {
            f16x8 af[4], bf[4];
            #pragma unroll
            for (int i = 0; i < 4; ++i) {
                af[i] = *(const f16x8*)(sA1 + (wm * 64 + i * 16 + col16) * 32 + kq);
                bf[i] = *(const f16x8*)(sB1 + (wn * 64 + i * 16 + col16) * 32 + kq);
            }
            #pragma unroll
            for (int mi = 0; mi < 4; ++mi)
                #pragma unroll
                for (int ni = 0; ni < 4; ++ni)
                    acc[mi][ni] = __builtin_amdgcn_mfma_f32_16x16x32_f16(
                        af[mi], bf[ni], acc[mi][ni], 0, 0, 0);
        }
    }

    const int quad = lane >> 4;
    if (!head) {
        #pragma unroll
        for (int ni = 0; ni < 4; ++ni) {
            const int n = n0 + wn * 64 + ni * 16 + col16;
            const float b = bias[n];
            const size_t cb = ((size_t)(n >> 5) * MPAD) * 32 + (n & 31);
            #pragma unroll
            for (int mi = 0; mi < 4; ++mi) {
                #pragma unroll
                for (int r = 0; r < 4; ++r) {
                    const int m = m0 + wm * 64 + mi * 16 + quad * 4 + r;
                    float v = fmaxf(acc[mi][ni][r] + b, 0.f);
                    C[cb + (size_t)m * 32] = (f16)v;   // K-chunk-tiled
                }
            }
        }
    } else {
        float bb[4], w3c[4][3];
        #pragma unroll
        for (int ni = 0; ni < 4; ++ni) {
            const int n = n0 + wn * 64 + ni * 16 + col16;
            bb[ni] = bias[n];
            #pragma unroll
            for (int jj = 0; jj < 3; ++jj) w3c[ni][jj] = W3[n * 3 + jj];
        }
        const bool addb3 = (blockIdx.y == 0 && wn == 0);
        #pragma unroll
        for (int mi = 0; mi < 4; ++mi) {
            #pragma unroll
            for (int r = 0; r < 4; ++r) {
                float s0 = 0.f, s1 = 0.f, s2 = 0.f;
                #pragma unroll
                for (int ni = 0; ni < 4; ++ni) {
                    float v = fmaxf(acc[mi][ni][r] + bb[ni], 0.f);
                    s0 += v * w3c[ni][0];
                    s1 += v * w3c[ni][1];
                    s2 += v * w3c[ni][2];
                }
                #pragma unroll
                for (int mask = 1; mask <= 8; mask <<= 1) {
                    s0 += __shfl_xor(s0, mask);
                    s1 += __shfl_xor(s1, mask);
                    s2 += __shfl_xor(s2, mask);
                }
                if (col16 == 0) {
                    const int m = m0 + wm * 64 + mi * 16 + quad * 4 + r;
                    if (m < NLINES) {
                        atomicAdd(&out[m * 3 + 0], s0 + (addb3 ? b3[0] : 0.f));
                        atomicAdd(&out[m * 3 + 1], s1 + (addb3 ? b3[1] : 0.f));
                        atomicAdd(&out[m * 3 + 2], s2 + (addb3 ? b3[2] : 0.f));
                    }
                }
            }
        }
    }
}

// ---------------------------------------------------------------------------
extern "C" void kernel_launch(void* const* d_in, const int* in_sizes, int n_in,
                              void* d_out, int out_size, void* d_ws, size_t ws_size,
                              hipStream_t stream)
{
    const float* jloc = (const float*)d_in[0];
    const float* joff = (const float*)d_in[1];
    const float* loi  = (const float*)d_in[2];
    const int*   eidx = (const int*)d_in[3];
    const float* W1   = (const float*)d_in[4];
    const float* b1   = (const float*)d_in[5];
    const float* W2   = (const float*)d_in[6];
    const float* b2   = (const float*)d_in[7];
    const float* W3   = (const float*)d_in[8];
    const float* b3   = (const float*)d_in[9];
    float* out = (float*)d_out;

    char* ws = (char*)d_ws;
    f16*   loiT  = (f16*)(ws);                            // 4 MB
    f16*   W1T   = (f16*)(ws + ((size_t)4 << 20));        // 2 MB
    f16*   W2T   = (f16*)(ws + ((size_t)6 << 20));        // 2 MB
    float* juncs = (float*)(ws + ((size_t)8 << 20));      // 2.4 KB
    int*   count = (int*)(ws + ((size_t)8 << 20) + 4096);
    unsigned long long* cand =
        (unsigned long long*)(ws + ((size_t)8 << 20) + 8192);  // 32 KB
    int*   order = (int*)(ws + ((size_t)8 << 20) + 65536);     // 80 KB
    f16*   feats = (f16*)(ws + ((size_t)9 << 20));        // 41.4 MB (tiled MPADx1024)
    f16*   h1    = (f16*)(ws + ((size_t)51 << 20));       // 41.4 MB (tiled)

    hipMemsetAsync(count, 0, sizeof(int), stream);
    preproc_kernel<<<dim3(764), dim3(256), 0, stream>>>(
        loi, loiT, W1, W1T, W2, W2T, jloc, cand, count, out, out_size);
    sort_lines_kernel<<<dim3(1), dim3(1024), 0, stream>>>(eidx, order);
    rank_junc_kernel<<<dim3(MAXCAND / 256), dim3(256), 0, stream>>>(
        cand, count, joff, juncs);
    sample_kernel<<<dim3(NLINES / 4), dim3(256), 0, stream>>>(
        loiT, juncs, eidx, order, feats);
    gemm_bias_relu_kernel<<<dim3(MPAD / 256, NDIM / 128), dim3(512), 0, stream>>>(
        feats, W1T, b1, h1, nullptr, nullptr, nullptr, KDIM, 0);
    gemm_bias_relu_kernel<<<dim3(MPAD / 256, NDIM / 128), dim3(512), 0, stream>>>(
        h1, W2T, b2, nullptr, W3, b3, out, KDIM, 1);
}

// Round 15
// 310.879 us; speedup vs baseline: 1.1592x; 1.1592x over previous
//
#include <hip/hip_runtime.h>
#include <cmath>

// ---------------------------------------------------------------------------
// WireframeDetector: NMS -> top-k 300 junctions -> line sampling (bilinear +
// maxpool) -> 3-layer MLP (fp16 MFMA for the two 1024x1024 GEMMs).
// R15: revert to R13 (best measured, 311 us). R14's BM=256/512-thread GEMM
//      (93->109 us, FETCH unchanged) and e0-sort (+17 us sample side) both
//      regressed. GEMM sits at its measured delivery wall: 643 MB staged at
//      ~6.9 TB/s -> 441 TF predicted == 441 TF measured.
// ---------------------------------------------------------------------------

typedef _Float16 f16;
typedef _Float16 f16x2 __attribute__((ext_vector_type(2)));
typedef _Float16 f16x8 __attribute__((ext_vector_type(8)));
typedef float f32x4 __attribute__((ext_vector_type(4)));

#define HWD 128
#define NPIX 16384            // 128*128
#define TOPK_N 300
#define NLINES 20000
#define MPAD 20096            // 157 * 128
#define KDIM 1024
#define NDIM 1024
#define MAXCAND 4096

// async global->LDS, 16B per lane; LDS dest = wave-uniform base + lane*16
#define G2L(gp, lp) __builtin_amdgcn_global_load_lds( \
    (const __attribute__((address_space(1))) void*)(gp), \
    (__attribute__((address_space(3))) void*)(lp), 16, 0, 0)

// ---------------------------------------------------------------------------
// Fused preprocessing, one dispatch of 764 blocks:
//   blocks 0..127   : transpose loi [C][H][W] fp32 -> loiT [H][W][C] fp16
//   blocks 128..639 : W1/W2 [K][N] fp32 -> K-chunk-tiled fp16
//                     Wt[((k>>5)*1024 + n)*32 + (k&31)]
//   blocks 640..703 : 3x3 NMS on jloc, survivors -> cand list (count pre-zeroed)
//   blocks 704..763 : zero out[60000] (consumed by gemm2's atomicAdd epilogue)
// ---------------------------------------------------------------------------
__global__ __launch_bounds__(256) void preproc_kernel(
    const float* __restrict__ loi, f16* __restrict__ loiT,
    const float* __restrict__ W1, f16* __restrict__ W1T,
    const float* __restrict__ W2, f16* __restrict__ W2T,
    const float* __restrict__ jloc, unsigned long long* __restrict__ cand,
    int* __restrict__ count, float* __restrict__ out, int out_n)
{
    const int bid = blockIdx.x;
    const int tid = threadIdx.x;
    if (bid < 128) {
        __shared__ f16 t[128 * 130];     // [x][c], +2 pad kills bank conflicts
        const int y = bid;
        #pragma unroll 4
        for (int it = 0; it < 64; ++it) {
            int idx = it * 256 + tid;    // c-major, x fast -> coalesced read
            int c = idx >> 7, x = idx & 127;
            t[x * 130 + c] = (f16)loi[c * NPIX + y * HWD + x];
        }
        __syncthreads();
        #pragma unroll
        for (int it = 0; it < 8; ++it) {
            int j = it * 256 + tid;      // 2048 chunks of 8 f16
            int x = j >> 4, cc = (j & 15) * 8;
            f16x8 v;
            #pragma unroll
            for (int u = 0; u < 8; ++u) v[u] = t[x * 130 + cc + u];
            *(f16x8*)(loiT + (y * HWD + x) * HWD + cc) = v;
        }
    } else if (bid < 640) {
        const int b = bid - 128;         // 0..511
        const float* W = (b < 256) ? W1 : W2;
        f16* Wt = (b < 256) ? W1T : W2T;
        const int bb = b & 255;
        __shared__ f16 t[64 * 66];
        const int k0 = (bb >> 4) * 64;
        const int n0 = (bb & 15) * 64;
        #pragma unroll 4
        for (int it = 0; it < 16; ++it) {
            int i = it * 256 + tid;      // coalesced read over n
            int r = i >> 6, c = i & 63;
            t[c * 66 + r] = (f16)W[(size_t)(k0 + r) * NDIM + n0 + c];
        }
        __syncthreads();
        #pragma unroll
        for (int it = 0; it < 2; ++it) {
            int j = it * 256 + tid;
            int nr = j >> 3, kc = (j & 7) * 8;
            f16x8 v;
            #pragma unroll
            for (int u = 0; u < 8; ++u) v[u] = t[nr * 66 + kc + u];
            const int kk = k0 + kc;      // multiple of 8
            *(f16x8*)(Wt + ((size_t)(kk >> 5) * NDIM + (n0 + nr)) * 32 + (kk & 31)) = v;
        }
    } else if (bid < 704) {
        const int p = (bid - 640) * 256 + tid;   // 64 blocks x 256 = 16384
        const int y = p >> 7, x = p & 127;
        const float c = jloc[p];
        float m = c;
        for (int dy = -1; dy <= 1; ++dy) {
            int yy = y + dy;
            if (yy < 0 || yy >= HWD) continue;
            for (int dx = -1; dx <= 1; ++dx) {
                int xx = x + dx;
                if (xx < 0 || xx >= HWD) continue;
                m = fmaxf(m, jloc[yy * HWD + xx]);
            }
        }
        if (c == m && c > 0.0f) {
            int pos = atomicAdd(count, 1);
            if (pos < MAXCAND) {
                unsigned int ub = __float_as_uint(c);
                cand[pos] = ((unsigned long long)ub << 32) |
                            (unsigned long long)(0xFFFFFFFFu - (unsigned int)p);
            }
        }
    } else {
        const int base = (bid - 704) * 1024 + tid * 4;   // 60 blocks cover 61440
        #pragma unroll
        for (int u = 0; u < 4; ++u)
            if (base + u < out_n) out[base + u] = 0.f;
    }
}

// ---------------------------------------------------------------------------
// Rank-select top-300, LDS-cached. Keys unique => ranks exact; matches
// jax.lax.top_k order (value desc, index asc).
// ---------------------------------------------------------------------------
__global__ __launch_bounds__(256) void rank_junc_kernel(
    const unsigned long long* __restrict__ cand, const int* __restrict__ count,
    const float* __restrict__ joff, float* __restrict__ juncs /* [300][2] */)
{
    __shared__ unsigned long long keys[MAXCAND];   // 32 KB
    const int n = min(*count, MAXCAND);
    const int t = blockIdx.x * 256 + threadIdx.x;  // 16 blocks = 4096 threads
    for (int i = threadIdx.x; i < n; i += 256)
        keys[i] = cand[i];
    __syncthreads();
    if (t >= n) return;
    const unsigned long long key = keys[t];
    int rank = 0;
    int j = 0;
    for (; j + 4 <= n; j += 4) {
        rank += (keys[j]     > key);
        rank += (keys[j + 1] > key);
        rank += (keys[j + 2] > key);
        rank += (keys[j + 3] > key);
    }
    for (; j < n; ++j) rank += (keys[j] > key);
    if (rank < TOPK_N) {
        unsigned int p = 0xFFFFFFFFu - (unsigned int)(key & 0xFFFFFFFFull);
        // x = idx%w + (sigmoid(joff0)-0.5) + 0.5 = idx%w + sigmoid(joff0)
        float sx = 1.0f / (1.0f + expf(-joff[p]));
        float sy = 1.0f / (1.0f + expf(-joff[NPIX + p]));
        juncs[2 * rank + 0] = (float)(p & 127) + sx;
        juncs[2 * rank + 1] = (float)(p >> 7) + sy;
    }
}

// ---------------------------------------------------------------------------
// Per-line sampling, deduplicated: the 4 tap offsets + 4 weights of each of
// the 32 points depend only on the point, not the channel — lanes 0..31
// compute them ONCE into LDS; the channel loop (all 64 lanes, 2 ch each)
// reads them as wave-uniform broadcasts. 4 lines/block (wave per line).
// Output feats in K-chunk-tiled layout (matches GEMM staging).
// ---------------------------------------------------------------------------
__global__ __launch_bounds__(256) void sample_kernel(
    const f16* __restrict__ loiT, const float* __restrict__ juncs,
    const int* __restrict__ edge_idx, f16* __restrict__ feats)
{
    const int wv = threadIdx.x >> 6;
    const int l = blockIdx.x * 4 + wv;
    const int lane = threadIdx.x & 63;

    __shared__ int   soff[4][32][4];   // channel-base element offsets
    __shared__ float swt[4][32][4];    // bilinear weights

    if (lane < 32) {
        const int e0 = edge_idx[2 * l], e1 = edge_idx[2 * l + 1];
        const float ux = juncs[2 * e0], uy = juncs[2 * e0 + 1];
        const float vx = juncs[2 * e1], vy = juncs[2 * e1 + 1];
        const int j = lane;
        const float t = (float)j * (1.0f / 31.0f);
        const float px = ux * t + vx * (1.0f - t) - 0.5f;
        const float py = uy * t + vy * (1.0f - t) - 0.5f;
        float fx0 = fminf(fmaxf(floorf(px), 0.0f), 127.0f);
        float fy0 = fminf(fmaxf(floorf(py), 0.0f), 127.0f);
        float fx1 = fminf(fx0 + 1.0f, 127.0f);
        float fy1 = fminf(fy0 + 1.0f, 127.0f);
        int ix0 = (int)fx0, iy0 = (int)fy0, ix1 = (int)fx1, iy1 = (int)fy1;
        soff[wv][j][0] = (iy0 * HWD + ix0) * HWD;
        soff[wv][j][1] = (iy1 * HWD + ix0) * HWD;
        soff[wv][j][2] = (iy0 * HWD + ix1) * HWD;
        soff[wv][j][3] = (iy1 * HWD + ix1) * HWD;
        swt[wv][j][0] = (fy1 - py) * (fx1 - px);
        swt[wv][j][1] = (py - fy0) * (fx1 - px);
        swt[wv][j][2] = (fy1 - py) * (px - fx0);
        swt[wv][j][3] = (py - fy0) * (px - fx0);
    }
    __syncthreads();

    const int c2 = lane * 2;
    f16x8 o0, o1;
    #pragma unroll
    for (int p = 0; p < 8; ++p) {
        float m0 = -INFINITY, m1 = -INFINITY;
        #pragma unroll
        for (int jj = 0; jj < 4; ++jj) {
            const int j = p * 4 + jj;
            const int b00 = soff[wv][j][0], b10 = soff[wv][j][1];
            const int b01 = soff[wv][j][2], b11 = soff[wv][j][3];
            const float w00 = swt[wv][j][0], w10 = swt[wv][j][1];
            const float w01 = swt[wv][j][2], w11 = swt[wv][j][3];
            f16x2 v00 = *(const f16x2*)(loiT + b00 + c2);
            f16x2 v10 = *(const f16x2*)(loiT + b10 + c2);
            f16x2 v01 = *(const f16x2*)(loiT + b01 + c2);
            f16x2 v11 = *(const f16x2*)(loiT + b11 + c2);
            float s0 = (float)v00.x * w00 + (float)v10.x * w10 +
                       (float)v01.x * w01 + (float)v11.x * w11;
            float s1 = (float)v00.y * w00 + (float)v10.y * w10 +
                       (float)v01.y * w01 + (float)v11.y * w11;
            m0 = fmaxf(m0, s0);
            m1 = fmaxf(m1, s1);
        }
        o0[p] = (f16)m0;   // feature k = 16*lane + p
        o1[p] = (f16)m1;   // feature k = 16*lane + 8 + p
    }
    // tiled: (l, k) -> ((k>>5)*MPAD + l)*32 + (k&31); k-chunk = lane>>1,
    // within-chunk = (lane&1)*16.
    f16* dst = feats + ((size_t)(lane >> 1) * MPAD + l) * 32 + (lane & 1) * 16;
    *(f16x8*)(dst) = o0;
    *(f16x8*)(dst + 8) = o1;
}

// ---------------------------------------------------------------------------
// GEMM: 128x128 tile, 256 threads (2x2 waves of 64x64 subtiles). Two BK=32
// tiles per round (one vmcnt(0)+barrier drain per 32 MFMAs), operands in
// K-chunk-tiled layout (each staged 8KB tile contiguous; G2L = 1KB bursts).
// LDS [row][32] f16 -> proven fragment/bank behavior. Structural floor of
// this family: staged 643MB at ~6.9 TB/s delivery (R2-R14 sweep: ordering,
// drains, occupancy, tile shape, layout, pipelining all neutral or worse).
// head=0: C = relu(A@Bt^T + bias), stored K-chunk-tiled fp16.
// head=1: v = relu(A@Bt^T + bias); out[m][j] += v . W3  (atomicAdd, + b3 once)
// ---------------------------------------------------------------------------
__global__ __launch_bounds__(256, 2) void gemm_bias_relu_kernel(
    const f16* __restrict__ A, const f16* __restrict__ Bt,
    const float* __restrict__ bias, f16* __restrict__ C,
    const float* __restrict__ W3, const float* __restrict__ b3,
    float* __restrict__ out, int K, int head)
{
    const int tid = threadIdx.x;
    const int wave = tid >> 6, lane = tid & 63;
    const int wm = wave >> 1, wn = wave & 1;
    const int m0 = blockIdx.x * 128;
    const int n0 = blockIdx.y * 128;

    __shared__ f16 sA0[128 * 32];
    __shared__ f16 sA1[128 * 32];
    __shared__ f16 sB0[128 * 32];
    __shared__ f16 sB1[128 * 32];

    f32x4 acc[4][4];
    #pragma unroll
    for (int mi = 0; mi < 4; ++mi)
        #pragma unroll
        for (int ni = 0; ni < 4; ++ni)
            acc[mi][ni] = (f32x4){0.f, 0.f, 0.f, 0.f};

    // Tiled staging: chunk c of A-tile = contiguous 4096 f16 at
    // A + (c*MPAD + m0)*32. Wave w stages segs {w, w+4} (1KB each);
    // lane i deposits/fetches seg_base + i*16B. Global == LDS order.
    const size_t strideA = (size_t)MPAD * 32;   // f16 per k-chunk
    const size_t strideB = (size_t)NDIM * 32;
    const f16* gA = A + (size_t)m0 * 32 + wave * 512 + lane * 8;
    const f16* gB = Bt + (size_t)n0 * 32 + wave * 512 + lane * 8;
    const int so0 = wave * 512;                 // + lane*16B implicit
    const int so1 = (wave + 4) * 512;

    const int col16 = lane & 15;
    const int kq = (lane >> 4) * 8;

    const int NC = K >> 5;                      // 32 k-chunks
    for (int c0 = 0; c0 < NC; c0 += 2) {
        const f16* a0 = gA + (size_t)c0 * strideA;
        const f16* a1 = a0 + strideA;
        const f16* b0 = gB + (size_t)c0 * strideB;
        const f16* b1 = b0 + strideB;
        __syncthreads();                      // prev round's LDS reads complete
        G2L(a0, sA0 + so0);
        G2L(a0 + 2048, sA0 + so1);
        G2L(b0, sB0 + so0);
        G2L(b0 + 2048, sB0 + so1);
        G2L(a1, sA1 + so0);
        G2L(a1 + 2048, sA1 + so1);
        G2L(b1, sB1 + so0);
        G2L(b1 + 2048, sB1 + so1);
        __builtin_amdgcn_s_waitcnt(0x0f70);   // vmcnt(0): own DMA done
        __syncthreads();                      // all waves' DMA done

        {
            f16x8 af[4], bf[4];
            #pragma unroll
            for (int i = 0; i < 4; ++i) {
                af[i] = *(const f16x8*)(sA0 + (wm * 64 + i * 16 + col16) * 32 + kq);
                bf[i] = *(const f16x8*)(sB0 + (wn * 64 + i * 16 + col16) * 32 + kq);
            }
            #pragma unroll
            for (int mi = 0; mi < 4; ++mi)
                #pragma unroll
                for (int ni = 0; ni < 4; ++ni)
                    acc[mi][ni] = __builtin_amdgcn_mfma_f32_16x16x32_f16(
                        af[mi], bf[ni], acc[mi][ni], 0, 0, 0);
        }
        {
            f16x8 af[4], bf[4];
            #pragma unroll
            for (int i = 0; i < 4; ++i) {
                af[i] = *(const f16x8*)(sA1 + (wm * 64 + i * 16 + col16) * 32 + kq);
                bf[i] = *(const f16x8*)(sB1 + (wn * 64 + i * 16 + col16) * 32 + kq);
            }
            #pragma unroll
            for (int mi = 0; mi < 4; ++mi)
                #pragma unroll
                for (int ni = 0; ni < 4; ++ni)
                    acc[mi][ni] = __builtin_amdgcn_mfma_f32_16x16x32_f16(
                        af[mi], bf[ni], acc[mi][ni], 0, 0, 0);
        }
    }

    const int quad = lane >> 4;
    if (!head) {
        #pragma unroll
        for (int ni = 0; ni < 4; ++ni) {
            const int n = n0 + wn * 64 + ni * 16 + col16;
            const float b = bias[n];
            const size_t cb = ((size_t)(n >> 5) * MPAD) * 32 + (n & 31);
            #pragma unroll
            for (int mi = 0; mi < 4; ++mi) {
                #pragma unroll
                for (int r = 0; r < 4; ++r) {
                    const int m = m0 + wm * 64 + mi * 16 + quad * 4 + r;
                    float v = fmaxf(acc[mi][ni][r] + b, 0.f);
                    C[cb + (size_t)m * 32] = (f16)v;   // K-chunk-tiled
                }
            }
        }
    } else {
        float bb[4], w3c[4][3];
        #pragma unroll
        for (int ni = 0; ni < 4; ++ni) {
            const int n = n0 + wn * 64 + ni * 16 + col16;
            bb[ni] = bias[n];
            #pragma unroll
            for (int jj = 0; jj < 3; ++jj) w3c[ni][jj] = W3[n * 3 + jj];
        }
        const bool addb3 = (blockIdx.y == 0 && wn == 0);
        #pragma unroll
        for (int mi = 0; mi < 4; ++mi) {
            #pragma unroll
            for (int r = 0; r < 4; ++r) {
                float s0 = 0.f, s1 = 0.f, s2 = 0.f;
                #pragma unroll
                for (int ni = 0; ni < 4; ++ni) {
                    float v = fmaxf(acc[mi][ni][r] + bb[ni], 0.f);
                    s0 += v * w3c[ni][0];
                    s1 += v * w3c[ni][1];
                    s2 += v * w3c[ni][2];
                }
                #pragma unroll
                for (int mask = 1; mask <= 8; mask <<= 1) {
                    s0 += __shfl_xor(s0, mask);
                    s1 += __shfl_xor(s1, mask);
                    s2 += __shfl_xor(s2, mask);
                }
                if (col16 == 0) {
                    const int m = m0 + wm * 64 + mi * 16 + quad * 4 + r;
                    if (m < NLINES) {
                        atomicAdd(&out[m * 3 + 0], s0 + (addb3 ? b3[0] : 0.f));
                        atomicAdd(&out[m * 3 + 1], s1 + (addb3 ? b3[1] : 0.f));
                        atomicAdd(&out[m * 3 + 2], s2 + (addb3 ? b3[2] : 0.f));
                    }
                }
            }
        }
    }
}

// ---------------------------------------------------------------------------
extern "C" void kernel_launch(void* const* d_in, const int* in_sizes, int n_in,
                              void* d_out, int out_size, void* d_ws, size_t ws_size,
                              hipStream_t stream)
{
    const float* jloc = (const float*)d_in[0];
    const float* joff = (const float*)d_in[1];
    const float* loi  = (const float*)d_in[2];
    const int*   eidx = (const int*)d_in[3];
    const float* W1   = (const float*)d_in[4];
    const float* b1   = (const float*)d_in[5];
    const float* W2   = (const float*)d_in[6];
    const float* b2   = (const float*)d_in[7];
    const float* W3   = (const float*)d_in[8];
    const float* b3   = (const float*)d_in[9];
    float* out = (float*)d_out;

    char* ws = (char*)d_ws;
    f16*   loiT  = (f16*)(ws);                            // 4 MB
    f16*   W1T   = (f16*)(ws + ((size_t)4 << 20));        // 2 MB
    f16*   W2T   = (f16*)(ws + ((size_t)6 << 20));        // 2 MB
    float* juncs = (float*)(ws + ((size_t)8 << 20));      // 2.4 KB
    int*   count = (int*)(ws + ((size_t)8 << 20) + 4096);
    unsigned long long* cand =
        (unsigned long long*)(ws + ((size_t)8 << 20) + 8192);  // 32 KB
    f16*   feats = (f16*)(ws + ((size_t)9 << 20));        // 40 MB (tiled MPADx1024)
    f16*   h1    = (f16*)(ws + ((size_t)51 << 20));       // 40 MB (tiled)

    hipMemsetAsync(count, 0, sizeof(int), stream);
    preproc_kernel<<<dim3(764), dim3(256), 0, stream>>>(
        loi, loiT, W1, W1T, W2, W2T, jloc, cand, count, out, out_size);
    rank_junc_kernel<<<dim3(MAXCAND / 256), dim3(256), 0, stream>>>(
        cand, count, joff, juncs);
    sample_kernel<<<dim3(NLINES / 4), dim3(256), 0, stream>>>(loiT, juncs, eidx, feats);
    gemm_bias_relu_kernel<<<dim3(MPAD / 128, NDIM / 128), dim3(256), 0, stream>>>(
        feats, W1T, b1, h1, nullptr, nullptr, nullptr, KDIM, 0);
    gemm_bias_relu_kernel<<<dim3(MPAD / 128, NDIM / 128), dim3(256), 0, stream>>>(
        h1, W2T, b2, nullptr, W3, b3, out, KDIM, 1);
}